// Round 6
// baseline (778.326 us; speedup 1.0000x reference)
//
#include <hip/hip_runtime.h>
#include <hip/hip_bf16.h>

typedef __attribute__((ext_vector_type(8))) short bf16x8;
typedef __attribute__((ext_vector_type(4))) short s16x4;
typedef __attribute__((ext_vector_type(4))) float f32x4;

__device__ __forceinline__ short f2bf(float f) {
  union { __hip_bfloat16 h; short s; } u;
  u.h = __float2bfloat16(f);
  return u.s;
}

__device__ __forceinline__ void gld_lds16(const short* g, short* l) {
  __builtin_amdgcn_global_load_lds((const __attribute__((address_space(1))) unsigned*)g,
                                   (__attribute__((address_space(3))) unsigned*)l,
                                   16, 0, 0);
}

#define BARX(N) asm volatile("s_waitcnt vmcnt(" #N ") lgkmcnt(0)\ns_barrier" ::: "memory")

// W[K][N] fp32 -> bf16 fragment slots: slot s = (kc*(N/16)+f)*64 + lane, lane=(kg,l16)
// content: W[k(kc*32+kg*8+e)][f*16+l16].  PERM: k-col permutation matching H storage:
// k = (kh & ~63) | ((kh&3)<<4) | ((kh>>2)&15)
template <bool PERM>
__global__ void prep_kernel(const float* __restrict__ W, short* __restrict__ out, int K, int N) {
  int s = blockIdx.x * 256 + threadIdx.x;
  int NF = N >> 4;
  int total = (K >> 5) * NF * 64;
  if (s >= total) return;
  int l = s & 63, kcf = s >> 6;
  int kc = kcf / NF, f = kcf - kc * NF;
  int kg = l >> 4, l16 = l & 15;
  bf16x8 o;
#pragma unroll
  for (int e = 0; e < 8; ++e) {
    int kh = kc * 32 + kg * 8 + e;
    int k = PERM ? ((kh & ~63) | ((kh & 3) << 4) | ((kh >> 2) & 15)) : kh;
    o[e] = f2bf(W[(size_t)k * N + f * 16 + l16]);
  }
  *(bf16x8*)(out + (size_t)s * 8) = o;
}

// ---------------- CSR aggregation ----------------
__global__ void count_kernel(const int* __restrict__ dst, int* __restrict__ cnt, int E) {
  int i = blockIdx.x * 256 + threadIdx.x;
  if (i < E) atomicAdd(&cnt[dst[i]], 1);
}

__global__ __launch_bounds__(1024) void scan_kernel(const int* __restrict__ cnt,
                                                    int* __restrict__ off,
                                                    int* __restrict__ cursor, int N) {
  __shared__ int wsum[16];
  const int t = threadIdx.x;
  const int w = t >> 6, l = t & 63;
  int running = 0;
  for (int base = 0; base < N; base += 1024) {
    int i = base + t;
    int v = (i < N) ? cnt[i] : 0;
    int x = v;
#pragma unroll
    for (int d = 1; d < 64; d <<= 1) { int y = __shfl_up(x, d); if (l >= d) x += y; }
    if (l == 63) wsum[w] = x;
    __syncthreads();
    if (w == 0) {
      int s = (l < 16) ? wsum[l] : 0;
#pragma unroll
      for (int d = 1; d < 16; d <<= 1) { int y = __shfl_up(s, d); if (l >= d) s += y; }
      if (l < 16) wsum[l] = s;
    }
    __syncthreads();
    int total = wsum[15];
    int wo = (w > 0) ? wsum[w - 1] : 0;
    int excl = running + wo + x - v;
    if (i < N) { off[i] = excl; cursor[i] = excl; }
    running += total;
    __syncthreads();
  }
  if (t == 0) off[N] = running;
}

__global__ void scatter_kernel(const int* __restrict__ dst, int* __restrict__ cursor,
                               int* __restrict__ eidx, int E) {
  int e = blockIdx.x * 256 + threadIdx.x;
  if (e < E) {
    int p = atomicAdd(&cursor[dst[e]], 1);
    eidx[p] = e;
  }
}

__global__ void agg_kernel(const float* __restrict__ edge_out, const int* __restrict__ eidx,
                           const int* __restrict__ off, float* __restrict__ agg, int N) {
  int n = blockIdx.x * 4 + (threadIdx.x >> 6);
  if (n >= N) return;
  int l = threadIdx.x & 63;
  int beg = off[n], end = off[n + 1];
  float ax = 0.f, ay = 0.f;
  int i = beg;
  for (; i + 4 <= end; i += 4) {
    int e0 = eidx[i], e1 = eidx[i + 1], e2 = eidx[i + 2], e3 = eidx[i + 3];
    float2 v0 = *(const float2*)(edge_out + (size_t)e0 * 128 + l * 2);
    float2 v1 = *(const float2*)(edge_out + (size_t)e1 * 128 + l * 2);
    float2 v2 = *(const float2*)(edge_out + (size_t)e2 * 128 + l * 2);
    float2 v3 = *(const float2*)(edge_out + (size_t)e3 * 128 + l * 2);
    ax += v0.x + v1.x + v2.x + v3.x;
    ay += v0.y + v1.y + v2.y + v3.y;
  }
  for (; i < end; ++i) {
    int e = eidx[i];
    float2 v = *(const float2*)(edge_out + (size_t)e * 128 + l * 2);
    ax += v.x; ay += v.y;
  }
  float inv = 1.0f / fmaxf((float)(end - beg), 1.0f);
  *(float2*)(agg + (size_t)n * 128 + l * 2) = make_float2(ax * inv, ay * inv);
}

struct F8 { float4 a, b; };

// ---------------- fused 3-layer MLP + LN, BM=64, 256 thr, 72 KB LDS (2 blocks/CU) ----------------
// L1/L2: col-split, wave w owns cols w*64..+63, all 64 rows (4x4 frags).
// L3: row-split, wave w owns rows w*16..+15, all 128 cols.
// Weight stream wAll = W1|W2|W3 contiguous in 8192-short (16 KB) units, one unit per interval,
// double-buffered, counted-vmcnt barrier per interval.
// H: addr_shorts(row, ch) = row*256 + (ch ^ ((row&7)<<3)); position ch within each 64-block
// holds col c = ((ch&3)<<4)|((ch>>2)&15) -- matches PERM'd W2/W3 K-order.
template <bool IS_EDGE>
__launch_bounds__(256, 2)
__global__ void mlp_kernel(const float* __restrict__ node_emb, const float* __restrict__ edge_emb,
                           const int* __restrict__ src, const int* __restrict__ dst,
                           const short* __restrict__ wAll,
                           const float* __restrict__ b1, const float* __restrict__ b2,
                           const float* __restrict__ b3,
                           const float* __restrict__ gam, const float* __restrict__ bet,
                           const float* __restrict__ agg,
                           float* __restrict__ out_base, int M) {
  extern __shared__ short smem[];
  short* Bs = smem;            // 2 x 8192 shorts (32 KB) weight double-buffer
  short* As = smem + 16384;    // 2 x 2048 shorts (8 KB) L1 A chunks
  short* Hs = smem + 20480;    // 16384 shorts (32 KB): 64 rows x 256 cols

  const int tid = threadIdx.x;
  const int m0 = blockIdx.x * 64;
  const int w = tid >> 6, lane = tid & 63, l16 = lane & 15, kg = lane >> 4;

  constexpr int NC1 = IS_EDGE ? 12 : 8;

  // gather role: thread stages row (tid>>2), 8 cols at (tid&3)*8 within 32-col chunk
  const int grow = tid >> 2;
  const int gk = tid & 3;
  const int grc = min(m0 + grow, M - 1);
  const int aslot = (grow >> 4) * 64 + gk * 16 + (grow & 15);
  int gsr = 0, gdr = 0;
  if (IS_EDGE) { gsr = src[grc]; gdr = dst[grc]; }

  // bias / LN param preload
  float b1v[4], b2v[4];
#pragma unroll
  for (int ct = 0; ct < 4; ++ct) {
    int col = w * 64 + ct * 16 + l16;
    b1v[ct] = b1[col];
    b2v[ct] = b2[col];
  }
  float b3v[8], gv[8], bev[8];
#pragma unroll
  for (int f = 0; f < 8; ++f) {
    int col = f * 16 + l16;
    b3v[f] = b3[col]; gv[f] = gam[col]; bev[f] = bet[col];
  }

  f32x4 acc[16];
#pragma unroll
  for (int i = 0; i < 16; ++i) { f32x4 z = {0.f, 0.f, 0.f, 0.f}; acc[i] = z; }

  auto stageU = [&](int v) {
    const short* g = wAll + (size_t)v * 8192;
    short* l = Bs + (size_t)(v & 1) * 8192;
#pragma unroll
    for (int s0 = 0; s0 < 4; ++s0)
      gld_lds16(g + (size_t)(s0 * 256 + tid) * 8, l + (size_t)(s0 * 256 + tid) * 8);
  };

  auto gatherA = [&](int c) -> F8 {
    const float* q;
    if (IS_EDGE) {
      if (c < 4)      q = node_emb + (size_t)gsr * 128 + c * 32 + gk * 8;
      else if (c < 8) q = node_emb + (size_t)gdr * 128 + (c - 4) * 32 + gk * 8;
      else            q = edge_emb + (size_t)grc * 128 + (c - 8) * 32 + gk * 8;
    } else {
      if (c < 4) q = node_emb + (size_t)grc * 128 + c * 32 + gk * 8;
      else       q = agg + (size_t)grc * 128 + (c - 4) * 32 + gk * 8;
    }
    F8 r;
    r.a = *(const float4*)q;
    r.b = *(const float4*)(q + 4);
    return r;
  };
  auto writeA = [&](const F8& p, int buf) {
    float t[8];
    *(float4*)t = p.a; *(float4*)(t + 4) = p.b;
    bf16x8 o;
#pragma unroll
    for (int e = 0; e < 8; ++e) o[e] = f2bf(t[e]);
    *(bf16x8*)&As[(size_t)buf * 2048 + (size_t)aslot * 8] = o;
  };

  auto mfma16 = [&](bf16x8* a, bf16x8* b) {
    __builtin_amdgcn_s_setprio(1);
#pragma unroll
    for (int rt = 0; rt < 4; ++rt)
#pragma unroll
      for (int ct = 0; ct < 4; ++ct)
        acc[rt * 4 + ct] = __builtin_amdgcn_mfma_f32_16x16x32_bf16(a[rt], b[ct], acc[rt * 4 + ct], 0, 0, 0);
    __builtin_amdgcn_s_setprio(0);
  };

  auto compA = [&](int i) {
    const short* Ap = As + (size_t)(i & 1) * 2048;
    const short* Bp = Bs + (size_t)(i & 1) * 8192;
    bf16x8 a[4], b[4];
#pragma unroll
    for (int rt = 0; rt < 4; ++rt)
      a[rt] = *(const bf16x8*)&Ap[(size_t)(rt * 64 + kg * 16 + l16) * 8];
#pragma unroll
    for (int ct = 0; ct < 4; ++ct)
      b[ct] = *(const bf16x8*)&Bp[(size_t)((w * 4 + ct) * 64 + lane) * 8];
    mfma16(a, b);
  };

  auto computeH = [&](int j, const short* Bp) {
    bf16x8 a[4], b[4];
#pragma unroll
    for (int rt = 0; rt < 4; ++rt) {
      int row = rt * 16 + l16;
      int ch = (j * 32 + kg * 8) ^ ((row & 7) << 3);
      a[rt] = *(const bf16x8*)&Hs[(size_t)row * 256 + ch];
    }
#pragma unroll
    for (int ct = 0; ct < 4; ++ct)
      b[ct] = *(const bf16x8*)&Bp[(size_t)((w * 4 + ct) * 64 + lane) * 8];
    mfma16(a, b);
  };

  auto writeH = [&](const float* bv) {
#pragma unroll
    for (int rt = 0; rt < 4; ++rt)
#pragma unroll
      for (int q = 0; q < 4; ++q) {
        int row = rt * 16 + kg * 4 + q;
        s16x4 v;
#pragma unroll
        for (int ct = 0; ct < 4; ++ct)
          v[ct] = f2bf(fmaxf(acc[rt * 4 + ct][q] + bv[ct], 0.f));
        int ch = (w * 64 + l16 * 4) ^ ((row & 7) << 3);
        *(s16x4*)&Hs[(size_t)row * 256 + ch] = v;
      }
#pragma unroll
    for (int i = 0; i < 16; ++i) { f32x4 z = {0.f, 0.f, 0.f, 0.f}; acc[i] = z; }
  };

  auto computeL3 = [&](int kk, const short* Bp) {  // kk = W3 32-chunk index 0..7
    int row = w * 16 + l16;
    int ch = (kk * 32 + kg * 8) ^ ((row & 7) << 3);
    bf16x8 a = *(const bf16x8*)&Hs[(size_t)row * 256 + ch];
    const short* Bsub = Bp + (size_t)(kk & 1) * 4096;
    __builtin_amdgcn_s_setprio(1);
#pragma unroll
    for (int f = 0; f < 8; ++f) {
      bf16x8 b = *(const bf16x8*)&Bsub[(size_t)(f * 64 + lane) * 8];
      acc[f] = __builtin_amdgcn_mfma_f32_16x16x32_bf16(a, b, acc[f], 0, 0, 0);
    }
    __builtin_amdgcn_s_setprio(0);
  };

  // ---- prologue ----
  F8 h0 = gatherA(0);
  stageU(0);
  __builtin_amdgcn_sched_barrier(0);
  F8 hold = gatherA(1);
  writeA(h0, 0);
  __builtin_amdgcn_sched_barrier(0);
  BARX(2);  // stage(0) done; gather(1) in flight

  // ---- layer 1 (K = NC1*32, N = 256) ----
#pragma unroll
  for (int i = 0; i < NC1; ++i) {
    stageU(i + 1);  // unit NC1 == first W2 unit when i == NC1-1
    __builtin_amdgcn_sched_barrier(0);
    F8 gnew = hold;
    if (i + 2 < NC1) gnew = gatherA(i + 2);
    __builtin_amdgcn_sched_barrier(0);
    compA(i);
    if (i + 1 < NC1) writeA(hold, (i + 1) & 1);
    __builtin_amdgcn_sched_barrier(0);
    if (i + 2 < NC1)      { BARX(2); }  // stage(i+1) done, gather(i+2) in flight
    else if (i + 1 < NC1) { BARX(0); }  // stage(i+1) done, nothing else
    else                  { BARX(4); }  // defer stage(NC1) drain to writeH barrier
    hold = gnew;
  }
  writeH(b1v);
  BARX(0);  // drain stage(NC1) + H1 writes visible

  // ---- layer 2 (K = 256, N = 256) ----
#pragma unroll
  for (int j = 0; j < 8; ++j) {
    int u = NC1 + j;
    stageU(u + 1);
    computeH(j, Bs + (size_t)(u & 1) * 8192);
    if (j < 7) { BARX(0); }
    else       { BARX(4); }  // defer first-W3-unit drain
  }
  writeH(b2v);
  BARX(0);

  // ---- layer 3 (K = 256, N = 128): 4 units of 2 chunks ----
#pragma unroll
  for (int k = 0; k < 4; ++k) {
    int u = NC1 + 8 + k;
    if (k < 3) stageU(u + 1);
    const short* Bp = Bs + (size_t)(u & 1) * 8192;
    computeL3(2 * k, Bp);
    computeL3(2 * k + 1, Bp);
    if (k < 3) { BARX(0); }
  }

  // ---- epilogue: bias + LayerNorm + residual ----
#pragma unroll
  for (int q = 0; q < 4; ++q) {
    int rg = m0 + w * 16 + kg * 4 + q;
    float o[8], s1 = 0.f, s2 = 0.f;
#pragma unroll
    for (int f = 0; f < 8; ++f) {
      float x = acc[f][q] + b3v[f];
      o[f] = x; s1 += x; s2 += x * x;
    }
#pragma unroll
    for (int m = 1; m <= 8; m <<= 1) { s1 += __shfl_xor(s1, m); s2 += __shfl_xor(s2, m); }
    float mu = s1 * (1.f / 128.f);
    float var = s2 * (1.f / 128.f) - mu * mu;
    float rs = rsqrtf(var + 1e-5f);
    if (rg < M) {
      const float* resid = (IS_EDGE ? edge_emb : node_emb) + (size_t)rg * 128;
      float* op = out_base + (size_t)rg * 128;
#pragma unroll
      for (int f = 0; f < 8; ++f) {
        int col = f * 16 + l16;
        op[col] = (o[f] - mu) * rs * gv[f] + bev[f] + resid[col];
      }
    }
  }
}

extern "C" void kernel_launch(void* const* d_in, const int* in_sizes, int n_in,
                              void* d_out, int out_size, void* d_ws, size_t ws_size,
                              hipStream_t stream) {
  const float* node_emb = (const float*)d_in[0];
  const float* edge_emb = (const float*)d_in[1];
  const int*   src      = (const int*)d_in[2];
  const int*   dst      = (const int*)d_in[3];
  const float* eW1 = (const float*)d_in[5];
  const float* eb1 = (const float*)d_in[6];
  const float* eW2 = (const float*)d_in[7];
  const float* eb2 = (const float*)d_in[8];
  const float* eW3 = (const float*)d_in[9];
  const float* eb3 = (const float*)d_in[10];
  const float* eg  = (const float*)d_in[11];
  const float* ebt = (const float*)d_in[12];
  const float* nW1 = (const float*)d_in[13];
  const float* nb1 = (const float*)d_in[14];
  const float* nW2 = (const float*)d_in[15];
  const float* nb2 = (const float*)d_in[16];
  const float* nW3 = (const float*)d_in[17];
  const float* nb3 = (const float*)d_in[18];
  const float* ng  = (const float*)d_in[19];
  const float* nbt = (const float*)d_in[20];

  const int Nn = in_sizes[0] / 128;
  const int Ee = in_sizes[2];

  char* ws = (char*)d_ws;
  float* agg  = (float*)ws;  ws += (size_t)Nn * 128 * 4;
  int* cnt_i  = (int*)ws;    ws += (size_t)Nn * 4;
  int* cursor = (int*)ws;    ws += (size_t)Nn * 4;
  int* offv   = (int*)ws;    ws += (size_t)(Nn + 1) * 4;
  int* eidx   = (int*)ws;    ws += (size_t)Ee * 4;
  ws = (char*)(((uintptr_t)ws + 15) & ~(uintptr_t)15);
  short* wp = (short*)ws;
  short* eAll = wp;                 // W1 (12x8192) | W2 (8x8192) | W3 (8x4096)
  short* nAll = wp + 196608;        // W1 (8x8192) | W2 (8x8192) | W3 (8x4096)

  float* out_node = (float*)d_out;
  float* out_edge = out_node + (size_t)Nn * 128;

  hipMemsetAsync(cnt_i, 0, (size_t)Nn * 4, stream);

  prep_kernel<false><<<48, 256, 0, stream>>>(eW1, eAll, 384, 256);
  prep_kernel<true><<<32, 256, 0, stream>>>(eW2, eAll + 98304, 256, 256);
  prep_kernel<true><<<16, 256, 0, stream>>>(eW3, eAll + 163840, 256, 128);
  prep_kernel<false><<<32, 256, 0, stream>>>(nW1, nAll, 256, 256);
  prep_kernel<true><<<32, 256, 0, stream>>>(nW2, nAll + 65536, 256, 256);
  prep_kernel<true><<<16, 256, 0, stream>>>(nW3, nAll + 131072, 256, 128);

  count_kernel<<<(Ee + 255) / 256, 256, 0, stream>>>(dst, cnt_i, Ee);
  scan_kernel<<<1, 1024, 0, stream>>>(cnt_i, offv, cursor, Nn);
  scatter_kernel<<<(Ee + 255) / 256, 256, 0, stream>>>(dst, cursor, eidx, Ee);

  mlp_kernel<true><<<(Ee + 63) / 64, 256, 73728, stream>>>(
      node_emb, edge_emb, src, dst, eAll,
      eb1, eb2, eb3, eg, ebt, agg, out_edge, Ee);

  agg_kernel<<<(Nn + 3) / 4, 256, 0, stream>>>(out_edge, eidx, offv, agg, Nn);

  mlp_kernel<false><<<(Nn + 63) / 64, 256, 73728, stream>>>(
      node_emb, edge_emb, src, dst, nAll,
      nb1, nb2, nb3, ng, nbt, agg, out_node, Nn);
}